// Round 1
// baseline (147.483 us; speedup 1.0000x reference)
//
#include <hip/hip_runtime.h>
#include <hip/hip_bf16.h>
#include <stdint.h>

#define B_ 32
#define L_ 4096
#define C_ 256
#define O_ 256
#define K_ 3
#define KN_ 4
#define A_ 16

typedef unsigned short u16;
typedef __attribute__((ext_vector_type(8))) short bf16x8;
typedef __attribute__((ext_vector_type(4))) float f32x4;

static __device__ __forceinline__ u16 f2bf(float f) {
    union { float f; uint32_t u; } v; v.f = f;
    uint32_t u = v.u;
    u += 0x7fffu + ((u >> 16) & 1u);   // round-to-nearest-even
    return (u16)(u >> 16);
}

// ---------------- kernel 1: pooling partials ----------------
// grid 1024 = b*32 + chunk ; block 256 (one c per thread); each block sums 128 rows.
__global__ __launch_bounds__(256) void pool_partial_k(const float* __restrict__ x,
                                                      float* __restrict__ part) {
    int bid = blockIdx.x;
    int b = bid >> 5, ch = bid & 31;
    int c = threadIdx.x;
    const float* p = x + (size_t)(b * L_ + ch * 128) * C_ + c;
    float s = 0.f;
    #pragma unroll 4
    for (int l = 0; l < 128; ++l) s += p[(size_t)l * C_];
    part[((size_t)bid << 8) + c] = s;
}

// ---------------- kernel 2: attention head (per-batch) ----------------
__global__ __launch_bounds__(256) void att_k(const float* __restrict__ part,
    const float* __restrict__ w_fc, const float* __restrict__ bn_g,
    const float* __restrict__ bn_b, const float* __restrict__ bn_m,
    const float* __restrict__ bn_v,
    const float* __restrict__ w_ch, const float* __restrict__ b_ch,
    const float* __restrict__ w_fil, const float* __restrict__ b_fil,
    const float* __restrict__ w_sp, const float* __restrict__ b_sp,
    const float* __restrict__ w_ker, const float* __restrict__ b_ker,
    float* __restrict__ ch_att, float* __restrict__ fil_att,
    float* __restrict__ sp_att, float* __restrict__ ker_att) {
    __shared__ float pooled[C_];
    __shared__ float h[A_];
    int b = blockIdx.x, t = threadIdx.x;
    float s = 0.f;
    for (int j = 0; j < 32; ++j) s += part[(((size_t)(b * 32 + j)) << 8) + t];
    pooled[t] = s * (1.0f / L_);
    __syncthreads();
    if (t < A_) {
        float acc = 0.f;
        for (int c = 0; c < C_; ++c) acc += pooled[c] * w_fc[t * C_ + c];
        float sc = bn_g[t] * rsqrtf(bn_v[t] + 1e-5f);
        acc = (acc - bn_m[t]) * sc + bn_b[t];
        h[t] = fmaxf(acc, 0.f);
    }
    __syncthreads();
    {
        float a1 = b_ch[t], a2 = b_fil[t];
        for (int a = 0; a < A_; ++a) { a1 += h[a] * w_ch[t * A_ + a]; a2 += h[a] * w_fil[t * A_ + a]; }
        ch_att[b * C_ + t]  = 1.f / (1.f + expf(-a1));
        fil_att[b * O_ + t] = 1.f / (1.f + expf(-a2));
    }
    if (t < K_) {
        float acc = b_sp[t];
        for (int a = 0; a < A_; ++a) acc += h[a] * w_sp[t * A_ + a];
        sp_att[b * 4 + t] = 1.f / (1.f + expf(-acc));
    }
    if (t == 0) {
        float lg[KN_], m = -1e30f;
        for (int n = 0; n < KN_; ++n) {
            float acc = b_ker[n];
            for (int a = 0; a < A_; ++a) acc += h[a] * w_ker[n * A_ + a];
            lg[n] = acc; m = fmaxf(m, acc);
        }
        float ss = 0.f;
        for (int n = 0; n < KN_; ++n) { lg[n] = expf(lg[n] - m); ss += lg[n]; }
        for (int n = 0; n < KN_; ++n) ker_att[b * 4 + n] = lg[n] / ss;
    }
}

// ---------------- kernel 3: effective weights -> bf16 MFMA-fragment layout ----------------
// W_frag element index = (((b*24+kc)*16+ob)*64+lane)*8 + e
//   kc = tap*8 + i/32 ; within-chunk k = (lane>>4)*8+e ; o = ob*16 + (lane&15)
__global__ __launch_bounds__(256) void wfrag_k(const float* __restrict__ weight,
    const float* __restrict__ ch_att, const float* __restrict__ fil_att,
    const float* __restrict__ sp_att, const float* __restrict__ ker_att,
    u16* __restrict__ wf) {
    int gid = blockIdx.x * 256 + threadIdx.x;      // 0 .. 786431
    int lane = gid & 63;
    int rest = gid >> 6;
    int ob = rest & 15; rest >>= 4;
    int kc = rest % 24; int b = rest / 24;
    int t  = kc >> 3;
    int i0 = ((kc & 7) << 5) + ((lane >> 4) << 3);
    int o  = (ob << 4) + (lane & 15);
    float k0 = ker_att[b * 4 + 0], k1 = ker_att[b * 4 + 1];
    float k2 = ker_att[b * 4 + 2], k3 = ker_att[b * 4 + 3];
    float fs = fil_att[b * O_ + o] * sp_att[b * 4 + t];
    const size_t nstr = (size_t)O_ * C_ * K_;
    const float* wb = weight + ((size_t)o * C_ + i0) * K_ + t;
    union { u16 h[8]; uint4 v; } pk;
    #pragma unroll
    for (int e = 0; e < 8; ++e) {
        const float* we = wb + e * K_;
        float acc = k0 * we[0] + k1 * we[nstr] + k2 * we[2 * nstr] + k3 * we[3 * nstr];
        acc *= fs * ch_att[b * C_ + i0 + e];
        pk.h[e] = f2bf(acc);
    }
    *reinterpret_cast<uint4*>(wf + (size_t)gid * 8) = pk.v;
}

// ---------------- kernel 4: dynamic conv as bf16 MFMA GEMM ----------------
// grid = b*32 + l-tile ; block 512 = 8 waves (wr=o-quadrant 0..3, wc=l-half 0..1)
// LDS: X-tile rows l0-1 .. l0+128 (130) x 256 ch, bf16, XOR slot swizzle.
__global__ __launch_bounds__(512, 2) void conv_k(const float* __restrict__ x,
    const u16* __restrict__ wf, float* __restrict__ out) {
    __shared__ uint4 lds4[4160];               // 66560 B
    char* lp = (char*)lds4;
    int bid = blockIdx.x;
    int b = bid >> 5, lb = bid & 31;
    int l0 = lb << 7;
    int tid = threadIdx.x;
    const size_t xbase = (size_t)b * L_ * C_;

    // ---- stage x tile (f32 -> bf16, swizzled) ----
    #pragma unroll 4
    for (int it = 0; it < 17; ++it) {
        int id = tid + (it << 9);
        if (id < 8320) {                        // 130 rows * 64 float4
            int r  = id >> 6;
            int i  = (id & 63) << 2;            // channel, multiple of 4
            int lg = l0 - 1 + r;
            float4 v = make_float4(0.f, 0.f, 0.f, 0.f);
            if (lg >= 0 && lg < L_)
                v = *reinterpret_cast<const float4*>(x + xbase + (size_t)lg * C_ + i);
            ushort4 hv;
            hv.x = f2bf(v.x); hv.y = f2bf(v.y); hv.z = f2bf(v.z); hv.w = f2bf(v.w);
            int slot = (i >> 3) ^ (r & 7);
            int off = r * 512 + slot * 16 + ((i >> 2) & 1) * 8;
            *reinterpret_cast<ushort4*>(lp + off) = hv;
        }
    }
    __syncthreads();

    int w = tid >> 6, lane = tid & 63;
    int wr = w & 3, wc = w >> 2;
    int lrow = lane & 15;
    int g = lane >> 4;

    f32x4 acc[4][4] = {};

    // ---- K loop: 24 chunks of 32 (tap-major), no barriers ----
    for (int kc = 0; kc < 24; ++kc) {
        int t  = kc >> 3;
        int ic = kc & 7;
        bf16x8 af[4], bfr[4];
        const u16* wp = wf + ((((size_t)(b * 24 + kc) * 16 + wr * 4) * 64 + lane) << 3);
        #pragma unroll
        for (int m = 0; m < 4; ++m)
            af[m] = *reinterpret_cast<const bf16x8*>(wp + (m << 9));
        int slotbase = (ic << 2) + g;
        #pragma unroll
        for (int n = 0; n < 4; ++n) {
            int row = wc * 64 + n * 16 + lrow + t;
            int off = row * 512 + ((slotbase ^ (row & 7)) << 4);
            bfr[n] = *reinterpret_cast<const bf16x8*>(lp + off);
        }
        #pragma unroll
        for (int m = 0; m < 4; ++m)
            #pragma unroll
            for (int n = 0; n < 4; ++n)
                acc[m][n] = __builtin_amdgcn_mfma_f32_16x16x32_bf16(af[m], bfr[n], acc[m][n], 0, 0, 0);
    }

    // ---- epilogue: C/D layout col=lane&15 (l), row=g*4+j (o) ----
    size_t obase = (size_t)b * O_ * L_;
    #pragma unroll
    for (int m = 0; m < 4; ++m) {
        int o0 = wr * 64 + m * 16 + g * 4;
        #pragma unroll
        for (int n = 0; n < 4; ++n) {
            int l = l0 + wc * 64 + n * 16 + lrow;
            #pragma unroll
            for (int j = 0; j < 4; ++j)
                out[obase + (size_t)(o0 + j) * L_ + l] = acc[m][n][j];
        }
    }
}

extern "C" void kernel_launch(void* const* d_in, const int* in_sizes, int n_in,
                              void* d_out, int out_size, void* d_ws, size_t ws_size,
                              hipStream_t stream) {
    const float* x      = (const float*)d_in[0];
    const float* weight = (const float*)d_in[1];
    const float* w_fc   = (const float*)d_in[2];
    const float* bn_g   = (const float*)d_in[3];
    const float* bn_b   = (const float*)d_in[4];
    const float* bn_m   = (const float*)d_in[5];
    const float* bn_v   = (const float*)d_in[6];
    const float* w_ch   = (const float*)d_in[7];
    const float* b_ch   = (const float*)d_in[8];
    const float* w_fil  = (const float*)d_in[9];
    const float* b_fil  = (const float*)d_in[10];
    const float* w_sp   = (const float*)d_in[11];
    const float* b_sp   = (const float*)d_in[12];
    const float* w_ker  = (const float*)d_in[13];
    const float* b_ker  = (const float*)d_in[14];
    float* out = (float*)d_out;
    char*  ws  = (char*)d_ws;

    float* part    = (float*)ws;                       // 32*32*256*4 = 1 MB
    float* ch_att  = (float*)(ws + (1 << 20));         // 32*256
    float* fil_att = ch_att + 32 * 256;                // 32*256
    float* sp_att  = fil_att + 32 * 256;               // 32*4
    float* ker_att = sp_att + 32 * 4;                  // 32*4
    u16*   wfrag   = (u16*)(ws + (1 << 20) + 70 * 1024); // 12.6 MB bf16

    pool_partial_k<<<1024, 256, 0, stream>>>(x, part);
    att_k<<<32, 256, 0, stream>>>(part, w_fc, bn_g, bn_b, bn_m, bn_v,
                                  w_ch, b_ch, w_fil, b_fil, w_sp, b_sp, w_ker, b_ker,
                                  ch_att, fil_att, sp_att, ker_att);
    wfrag_k<<<3072, 256, 0, stream>>>(weight, ch_att, fil_att, sp_att, ker_att, wfrag);
    conv_k<<<1024, 512, 0, stream>>>(x, wfrag, out);
}

// Round 2
// 107.484 us; speedup vs baseline: 1.3721x; 1.3721x over previous
//
#include <hip/hip_runtime.h>
#include <hip/hip_bf16.h>
#include <stdint.h>

#define B_ 32
#define L_ 4096
#define C_ 256
#define O_ 256
#define K_ 3
#define KN_ 4
#define A_ 16

typedef unsigned short u16;
typedef __attribute__((ext_vector_type(8))) short bf16x8;
typedef __attribute__((ext_vector_type(4))) float f32x4;

static __device__ __forceinline__ u16 f2bf(float f) {
    union { float f; uint32_t u; } v; v.f = f;
    uint32_t u = v.u;
    u += 0x7fffu + ((u >> 16) & 1u);   // round-to-nearest-even
    return (u16)(u >> 16);
}

// ---------------- kernel 1: pooling partials ----------------
__global__ __launch_bounds__(256) void pool_partial_k(const float* __restrict__ x,
                                                      float* __restrict__ part) {
    int bid = blockIdx.x;
    int b = bid >> 5, ch = bid & 31;
    int c = threadIdx.x;
    const float* p = x + (size_t)(b * L_ + ch * 128) * C_ + c;
    float s = 0.f;
    #pragma unroll 4
    for (int l = 0; l < 128; ++l) s += p[(size_t)l * C_];
    part[((size_t)bid << 8) + c] = s;
}

// ---------------- kernel 2: attention head (per-batch) ----------------
__global__ __launch_bounds__(256) void att_k(const float* __restrict__ part,
    const float* __restrict__ w_fc, const float* __restrict__ bn_g,
    const float* __restrict__ bn_b, const float* __restrict__ bn_m,
    const float* __restrict__ bn_v,
    const float* __restrict__ w_ch, const float* __restrict__ b_ch,
    const float* __restrict__ w_fil, const float* __restrict__ b_fil,
    const float* __restrict__ w_sp, const float* __restrict__ b_sp,
    const float* __restrict__ w_ker, const float* __restrict__ b_ker,
    float* __restrict__ ch_att, float* __restrict__ fil_att,
    float* __restrict__ sp_att, float* __restrict__ ker_att) {
    __shared__ float pooled[C_];
    __shared__ float h[A_];
    int b = blockIdx.x, t = threadIdx.x;
    float s = 0.f;
    for (int j = 0; j < 32; ++j) s += part[(((size_t)(b * 32 + j)) << 8) + t];
    pooled[t] = s * (1.0f / L_);
    __syncthreads();
    if (t < A_) {
        float acc = 0.f;
        for (int c = 0; c < C_; ++c) acc += pooled[c] * w_fc[t * C_ + c];
        float sc = bn_g[t] * rsqrtf(bn_v[t] + 1e-5f);
        acc = (acc - bn_m[t]) * sc + bn_b[t];
        h[t] = fmaxf(acc, 0.f);
    }
    __syncthreads();
    {
        float a1 = b_ch[t], a2 = b_fil[t];
        for (int a = 0; a < A_; ++a) { a1 += h[a] * w_ch[t * A_ + a]; a2 += h[a] * w_fil[t * A_ + a]; }
        ch_att[b * C_ + t]  = 1.f / (1.f + expf(-a1));
        fil_att[b * O_ + t] = 1.f / (1.f + expf(-a2));
    }
    if (t < K_) {
        float acc = b_sp[t];
        for (int a = 0; a < A_; ++a) acc += h[a] * w_sp[t * A_ + a];
        sp_att[b * 4 + t] = 1.f / (1.f + expf(-acc));
    }
    if (t == 0) {
        float lg[KN_], m = -1e30f;
        for (int n = 0; n < KN_; ++n) {
            float acc = b_ker[n];
            for (int a = 0; a < A_; ++a) acc += h[a] * w_ker[n * A_ + a];
            lg[n] = acc; m = fmaxf(m, acc);
        }
        float ss = 0.f;
        for (int n = 0; n < KN_; ++n) { lg[n] = expf(lg[n] - m); ss += lg[n]; }
        for (int n = 0; n < KN_; ++n) ker_att[b * 4 + n] = lg[n] / ss;
    }
}

// ---------------- kernel 3: effective weights -> bf16 MFMA-fragment layout ----------------
// wf element index = (((b*24 + tap*8 + ic)*16 + ob)*64 + lane)*8 + e
//   o = ob*16 + (lane&15) ; i = ic*32 + (lane>>4)*8 + e
// Block = (ob, ic, bg): stage weight sub-block [4n][16o][32i][3k] in LDS with
// coalesced reads (weight read exactly once), hoist per-lane 96 weights to
// registers, then loop over 8 b with fully-coalesced 16B stores.
__global__ __launch_bounds__(256) void wfrag_k(const float* __restrict__ weight,
    const float* __restrict__ ch_att, const float* __restrict__ fil_att,
    const float* __restrict__ sp_att, const float* __restrict__ ker_att,
    u16* __restrict__ wf) {
    __shared__ float wlds[64 * 97];            // row r=(n*16+o_l), 96 floats + 1 pad
    int beta = blockIdx.x;
    int ob = beta & 15, ic = (beta >> 4) & 7, bg = beta >> 7;   // bg 0..3
    int t = threadIdx.x;

    // phase 1: coalesced load of 6144 floats
    const size_t blk_base = (size_t)(ob * 16) * 768 + ic * 96;  // + n*256*768 + o_l*768
    #pragma unroll
    for (int j = 0; j < 24; ++j) {
        int ei = t + (j << 8);
        int r = ei / 96, c = ei - r * 96;
        int n = r >> 4, ol = r & 15;
        wlds[r * 97 + c] = weight[((size_t)n * 256 + ol) * 768 + blk_base + c];
    }
    __syncthreads();

    // phase 2
    int lane = t & 63, q = t >> 6;
    int o_l = lane & 15, ig = lane >> 4;
    int i0 = ig << 3;
    int o = (ob << 4) + o_l;
    int ig0 = (ic << 5) + i0;                  // global channel base

    float wl[4][3][8];
    #pragma unroll
    for (int n = 0; n < 4; ++n) {
        int rb = (n * 16 + o_l) * 97;
        #pragma unroll
        for (int e = 0; e < 8; ++e) {
            int cb = rb + (i0 + e) * 3;
            wl[n][0][e] = wlds[cb];
            wl[n][1][e] = wlds[cb + 1];
            wl[n][2][e] = wlds[cb + 2];
        }
    }

    #pragma unroll
    for (int bi = 0; bi < 2; ++bi) {
        int b = (bg << 3) + (q << 1) + bi;
        float ka0 = ker_att[b * 4 + 0], ka1 = ker_att[b * 4 + 1];
        float ka2 = ker_att[b * 4 + 2], ka3 = ker_att[b * 4 + 3];
        float fil = fil_att[b * O_ + o];
        float ch8[8];
        *reinterpret_cast<float4*>(ch8)     = *reinterpret_cast<const float4*>(ch_att + b * C_ + ig0);
        *reinterpret_cast<float4*>(ch8 + 4) = *reinterpret_cast<const float4*>(ch_att + b * C_ + ig0 + 4);
        #pragma unroll
        for (int tap = 0; tap < 3; ++tap) {
            float fs = fil * sp_att[b * 4 + tap];
            union { u16 h[8]; uint4 v; } pk;
            #pragma unroll
            for (int e = 0; e < 8; ++e) {
                float acc = ka0 * wl[0][tap][e] + ka1 * wl[1][tap][e]
                          + ka2 * wl[2][tap][e] + ka3 * wl[3][tap][e];
                pk.h[e] = f2bf(acc * fs * ch8[e]);
            }
            size_t idx = ((((size_t)(b * 24 + tap * 8 + ic) * 16 + ob) * 64) + lane) << 3;
            *reinterpret_cast<uint4*>(wf + idx) = pk.v;
        }
    }
}

// ---------------- kernel 4: dynamic conv as bf16 MFMA GEMM ----------------
// grid = 1024 (XCD-chunked swizzle); block 512 = 8 waves (wr 0..3 o-quad, wc 0..1 l-half)
// LDS: X-tile rows l0-1 .. l0+128 (130) x 256 ch bf16, XOR slot swizzle (66560 B).
// Epilogue reuses LDS as 8 x 8KB per-wave transpose buffers (swizzled, 256B stores).
__global__ __launch_bounds__(512, 4) void conv_k(const float* __restrict__ x,
    const u16* __restrict__ wf, float* __restrict__ out) {
    __shared__ uint4 lds4[4160];               // 66560 B
    char* lp = (char*)lds4;
    int phys = blockIdx.x;
    int logical = ((phys & 7) << 7) + (phys >> 3);   // XCD-chunked: 4 consecutive b / XCD
    int b = logical >> 5, lb = logical & 31;
    int l0 = lb << 7;
    int tid = threadIdx.x;
    const size_t xbase = (size_t)b * L_ * C_;

    // ---- stage x tile (f32 -> bf16, swizzled) ----
    #pragma unroll 4
    for (int it = 0; it < 17; ++it) {
        int id = tid + (it << 9);
        if (id < 8320) {                        // 130 rows * 64 float4
            int r  = id >> 6;
            int i  = (id & 63) << 2;
            int lg = l0 - 1 + r;
            float4 v = make_float4(0.f, 0.f, 0.f, 0.f);
            if (lg >= 0 && lg < L_)
                v = *reinterpret_cast<const float4*>(x + xbase + (size_t)lg * C_ + i);
            ushort4 hv;
            hv.x = f2bf(v.x); hv.y = f2bf(v.y); hv.z = f2bf(v.z); hv.w = f2bf(v.w);
            int slot = (i >> 3) ^ (r & 7);
            int off = r * 512 + slot * 16 + ((i >> 2) & 1) * 8;
            *reinterpret_cast<ushort4*>(lp + off) = hv;
        }
    }
    __syncthreads();

    int w = tid >> 6, lane = tid & 63;
    int wr = w & 3, wc = w >> 2;
    int lrow = lane & 15;
    int g = lane >> 4;

    f32x4 acc[4][4] = {};

    // ---- K loop: 24 chunks of 32 (tap-major), no barriers ----
    for (int kc = 0; kc < 24; ++kc) {
        int t  = kc >> 3;
        int ic = kc & 7;
        bf16x8 af[4], bfr[4];
        const u16* wp = wf + ((((size_t)(b * 24 + kc) * 16 + wr * 4) * 64 + lane) << 3);
        #pragma unroll
        for (int m = 0; m < 4; ++m)
            af[m] = *reinterpret_cast<const bf16x8*>(wp + (m << 9));
        int slotbase = (ic << 2) + g;
        #pragma unroll
        for (int n = 0; n < 4; ++n) {
            int row = wc * 64 + n * 16 + lrow + t;
            int off = row * 512 + ((slotbase ^ (row & 7)) << 4);
            bfr[n] = *reinterpret_cast<const bf16x8*>(lp + off);
        }
        #pragma unroll
        for (int m = 0; m < 4; ++m)
            #pragma unroll
            for (int n = 0; n < 4; ++n)
                acc[m][n] = __builtin_amdgcn_mfma_f32_16x16x32_bf16(af[m], bfr[n], acc[m][n], 0, 0, 0);
    }

    __syncthreads();   // all waves done reading the x tile; LDS is reused below

    // ---- epilogue: per-wave LDS transpose -> 256B-run global stores ----
    // wave region: 8KB at w*8192; logical [32 o_loc][64 l_loc] f32 with
    // 16B-slot swizzle: word = o_loc*64 + (((l_loc>>2)^o_loc)&15)*4 + (l_loc&3)
    float* ep = (float*)(lp + w * 8192);
    size_t obase = (size_t)b * O_ * L_;
    int lcol = l0 + wc * 64;
    #pragma unroll
    for (int c2 = 0; c2 < 2; ++c2) {
        #pragma unroll
        for (int m2 = 0; m2 < 2; ++m2) {
            int m = c2 * 2 + m2;
            #pragma unroll
            for (int n = 0; n < 4; ++n) {
                int l_loc = n * 16 + lrow;
                int sl = (l_loc >> 2);
                #pragma unroll
                for (int j = 0; j < 4; ++j) {
                    int o_loc = m2 * 16 + g * 4 + j;
                    ep[o_loc * 64 + ((sl ^ o_loc) & 15) * 4 + (l_loc & 3)] = acc[m][n][j];
                }
            }
        }
        // read back + store: 4 o-rows x 64 l per instruction (4 x 256B runs)
        #pragma unroll
        for (int og = 0; og < 8; ++og) {
            int o_loc = og * 4 + g;
            int l4 = lrow;                       // float4 slot index
            float4 v = *reinterpret_cast<float4*>(ep + o_loc * 64 + ((l4 ^ o_loc) & 15) * 4);
            int o = wr * 64 + c2 * 32 + o_loc;
            *reinterpret_cast<float4*>(out + obase + (size_t)o * L_ + lcol + l4 * 4) = v;
        }
        if (c2 == 0) __syncthreads();            // wave-local reuse; cheap safety barrier
    }
}

extern "C" void kernel_launch(void* const* d_in, const int* in_sizes, int n_in,
                              void* d_out, int out_size, void* d_ws, size_t ws_size,
                              hipStream_t stream) {
    const float* x      = (const float*)d_in[0];
    const float* weight = (const float*)d_in[1];
    const float* w_fc   = (const float*)d_in[2];
    const float* bn_g   = (const float*)d_in[3];
    const float* bn_b   = (const float*)d_in[4];
    const float* bn_m   = (const float*)d_in[5];
    const float* bn_v   = (const float*)d_in[6];
    const float* w_ch   = (const float*)d_in[7];
    const float* b_ch   = (const float*)d_in[8];
    const float* w_fil  = (const float*)d_in[9];
    const float* b_fil  = (const float*)d_in[10];
    const float* w_sp   = (const float*)d_in[11];
    const float* b_sp   = (const float*)d_in[12];
    const float* w_ker  = (const float*)d_in[13];
    const float* b_ker  = (const float*)d_in[14];
    float* out = (float*)d_out;
    char*  ws  = (char*)d_ws;

    float* part    = (float*)ws;                       // 1 MB
    float* ch_att  = (float*)(ws + (1 << 20));
    float* fil_att = ch_att + 32 * 256;
    float* sp_att  = fil_att + 32 * 256;
    float* ker_att = sp_att + 32 * 4;
    u16*   wfrag   = (u16*)(ws + (1 << 20) + 70 * 1024); // 12.6 MB bf16

    pool_partial_k<<<1024, 256, 0, stream>>>(x, part);
    att_k<<<32, 256, 0, stream>>>(part, w_fc, bn_g, bn_b, bn_m, bn_v,
                                  w_ch, b_ch, w_fil, b_fil, w_sp, b_sp, w_ker, b_ker,
                                  ch_att, fil_att, sp_att, ker_att);
    wfrag_k<<<512, 256, 0, stream>>>(weight, ch_att, fil_att, sp_att, ker_att, wfrag);
    conv_k<<<1024, 512, 0, stream>>>(x, wfrag, out);
}